// Round 3
// baseline (102.503 us; speedup 1.0000x reference)
//
#include <hip/hip_runtime.h>
#include <hip/hip_bf16.h>

typedef int   intx8   __attribute__((ext_vector_type(8)));
typedef int   intx4   __attribute__((ext_vector_type(4)));
typedef float floatx4 __attribute__((ext_vector_type(4)));

static constexpr int TWO_B = 8192;   // 2*B rows
static constexpr int CDIM  = 128;    // feature dim
static constexpr int NSPL  = 16;     // column splits (R6-proven)
// exp(x/T) = exp2(x * (1/T)/ln2), T = 0.5
#define SCALE 2.8853900817779268f
#define SQS   1.6986436f             // sqrt(SCALE): n8 rows pre-scaled by this,
                                     // so MFMA output is already in exp2 domain
#define INV_T 2.0f

#if __has_builtin(__builtin_amdgcn_exp2f)
#define EXP2F(x) __builtin_amdgcn_exp2f(x)
#else
#define EXP2F(x) exp2f(x)
#endif

// e8m0 scale byte 0x7F = 2^0 = 1.0 in all four byte slots
#define SCL1 0x7F7F7F7F

// ---------------------------------------------------------------------------
// Kernel 1: pair-structured normalize, 2 pairs per wave (512 blocks).
// [unchanged]
// ---------------------------------------------------------------------------
__global__ __launch_bounds__(256) void nk(const float* __restrict__ zi,
                                          const float* __restrict__ zj,
                                          unsigned char* __restrict__ n8,
                                          float* __restrict__ posv,
                                          float* __restrict__ sqv,
                                          float* __restrict__ outz) {
    if (blockIdx.x == 0 && threadIdx.x == 0) *outz = 0.0f;
    const int w = threadIdx.x >> 6, lane = threadIdx.x & 63;
    const int half = lane >> 5;            // 0: zi row, 1: zj row
    const int l32  = lane & 31;
#pragma unroll
    for (int pi = 0; pi < 2; ++pi) {
        const int pr = (blockIdx.x * 4 + w) * 2 + pi;   // pair index 0..4095
        const float* src = half ? (zj + (size_t)pr * CDIM) : (zi + (size_t)pr * CDIM);
        float4 x = reinterpret_cast<const float4*>(src)[l32];
        float ss = x.x * x.x + x.y * x.y + x.z * x.z + x.w * x.w;
#pragma unroll
        for (int m = 1; m < 32; m <<= 1) ss += __shfl_xor(ss, m, 64);  // within-half
        const float rn = rsqrtf(ss);
        float4 y; y.x = x.x * rn; y.y = x.y * rn; y.z = x.z * rn; y.w = x.w * rn;

        // fp32-exact positive dot: cross-half partner lanes.
        const float qx = __shfl_xor(y.x, 32, 64);
        const float qy = __shfl_xor(y.y, 32, 64);
        const float qz = __shfl_xor(y.z, 32, 64);
        const float qw = __shfl_xor(y.w, 32, 64);
        float d = y.x * qx + y.y * qy + y.z * qz + y.w * qw;
#pragma unroll
        for (int m = 1; m < 32; m <<= 1) d += __shfl_xor(d, m, 64);

        // fp8 row, pre-scaled so MFMA output is SCALE*sim.
        int p = __builtin_amdgcn_cvt_pk_fp8_f32(y.x * SQS, y.y * SQS, 0, false);
        p     = __builtin_amdgcn_cvt_pk_fp8_f32(y.z * SQS, y.w * SQS, p, true);
        const int row = pr + half * 4096;
        reinterpret_cast<int*>(n8 + (size_t)row * CDIM)[l32] = p;

        // self-sq from the stored bytes (already in exp2 domain).
        const float f0 = __builtin_amdgcn_cvt_f32_fp8(p, 0);
        const float f1 = __builtin_amdgcn_cvt_f32_fp8(p, 1);
        const float f2 = __builtin_amdgcn_cvt_f32_fp8(p, 2);
        const float f3 = __builtin_amdgcn_cvt_f32_fp8(p, 3);
        float sq = f0 * f0 + f1 * f1 + f2 * f2 + f3 * f3;
#pragma unroll
        for (int m = 1; m < 32; m <<= 1) sq += __shfl_xor(sq, m, 64);

        if (l32 == 0) { posv[row] = d; sqv[row] = sq; }
    }
}

// ---------------------------------------------------------------------------
// Kernel 2 [THIS ROUND]: cut duplicated LDS B-reads 2x by splitting N across
// wave pairs. 8 waves = 4 row-groups (64 rows each, afrag[4]) x 2 ni-halves
// (each wave reads only 2 of the 4 B-fragments per stage -> 4 ds_read_b128
// instead of 8; block total 64 -> 32 per stage). MFMA/wave/stage unchanged
// (2 nj x 4 mi = 8). Each row's exp-sum is produced jointly by its 2
// ni-waves; a 1 KB LDS scratch + one barrier combines them before the
// partial[] write, so fk is unchanged. Staging/vmcnt structure = R2.
// Per-row summation tree changes (two halves combined at end) -> absmax may
// become ~1e-6 instead of bit-exact; acceptable.
// ---------------------------------------------------------------------------
__global__ __launch_bounds__(512, 4) void sk(const unsigned char* __restrict__ n8,
                                             float* __restrict__ partial) {
    const int rt  = blockIdx.x;   // 0..31
    const int csp = blockIdx.y;   // 0..15
    const int tid = threadIdx.x;
    const int w   = tid >> 6;     // 0..7
    const int rg  = w >> 1;       // row-group 0..3 (64 rows each)
    const int ng  = w & 1;        // ni-half 0..1 (cols ng*32..+32 of each stage)
    const int lane = tid & 63;
    const int l15 = lane & 15;
    const int lg  = lane >> 4;

    __shared__ __align__(16) unsigned char ldsB[2][64 * CDIM];   // 2 x 8 KB
    __shared__ float red[256];                                   // 1 KB combine scratch

    // A fragments: 64 rows x 128 k per wave, registers.
    // f8f6f4 16x16x128 A-layout: m = lane&15, k = (lane>>4)*32 + j
    const int rowbase = rt * 256 + rg * 64;
    intx8 afrag[4];
#pragma unroll
    for (int mi = 0; mi < 4; ++mi)
        afrag[mi] = *reinterpret_cast<const intx8*>(
            n8 + (size_t)(rowbase + mi * 16 + l15) * CDIM + lg * 32);

    float rowsum[4][4];
#pragma unroll
    for (int mi = 0; mi < 4; ++mi)
#pragma unroll
        for (int r = 0; r < 4; ++r) rowsum[mi][r] = 0.0f;

    const int colbase0 = csp * 512;

    // Issue the single global_load_lds for column-stage ct into ldsB[buf].
    // LDS 16B-slot s holds global chunk (R = s>>3, c = (s&7) ^ (R&7)) —
    // swizzle on the global side (global_load_lds dest is lane-linear).
    auto stage = [&](int buf, int ct) {
        const int s = tid;                        // 0..511: uniform base + lane*16
        const int R = s >> 3, cs = s & 7;
        const int gc = cs ^ (R & 7);
        const unsigned char* g =
            n8 + (size_t)(colbase0 + ct * 64 + R) * CDIM + gc * 16;
        __builtin_amdgcn_global_load_lds(
            (__attribute__((address_space(1))) void*)g,
            (__attribute__((address_space(3))) void*)(&ldsB[buf][0] + s * 16),
            16, 0, 0);
    };

    stage(0, 0);   // prologue: stage-0 load in flight

#pragma unroll
    for (int ct = 0; ct < 8; ++ct) {
        const int cur = ct & 1;
        if (ct < 7) {
            stage(cur ^ 1, ct + 1);               // prefetch next stage
            // wait only for stage-ct's load; the prefetch load stays in
            // flight across the barrier (never drain to 0 mid-loop).
            asm volatile("s_waitcnt vmcnt(1)" ::: "memory");
        } else {
            asm volatile("s_waitcnt vmcnt(0)" ::: "memory");
        }
        __builtin_amdgcn_s_barrier();
        asm volatile("" ::: "memory");            // pin ds_reads below barrier

#pragma unroll
        for (int nj = 0; nj < 2; ++nj) {
            const int ni = ng * 2 + nj;           // this wave's B-fragment
            // B-layout: n = lane&15 (local row R), k = (lane>>4)*32 + j
            const int R  = ni * 16 + l15;
            const int c0 = lg * 2;
            const int p0 = R * 8 + (c0 ^ (R & 7));
            const int p1 = R * 8 + ((c0 + 1) ^ (R & 7));
            intx4 blo = *reinterpret_cast<const intx4*>(&ldsB[cur][0] + p0 * 16);
            intx4 bhi = *reinterpret_cast<const intx4*>(&ldsB[cur][0] + p1 * 16);
            intx8 bfrag;
            bfrag[0] = blo[0]; bfrag[1] = blo[1]; bfrag[2] = blo[2]; bfrag[3] = blo[3];
            bfrag[4] = bhi[0]; bfrag[5] = bhi[1]; bfrag[6] = bhi[2]; bfrag[7] = bhi[3];
#pragma unroll
            for (int mi = 0; mi < 4; ++mi) {
                floatx4 acc = {0.f, 0.f, 0.f, 0.f};
                acc = __builtin_amdgcn_mfma_scale_f32_16x16x128_f8f6f4(
                    afrag[mi], bfrag, acc, 0, 0, 0, SCL1, 0, SCL1);
                // C/D layout: col = lane&15, row = (lane>>4)*4 + reg
#pragma unroll
                for (int r = 0; r < 4; ++r)
                    rowsum[mi][r] += EXP2F(acc[r]);   // acc is already SCALE*sim
            }
        }

        if (ct < 7) {
            // all waves done reading ldsB[cur] before stage ct+2 overwrites it
            asm volatile("" ::: "memory");
            __builtin_amdgcn_s_barrier();
        }
    }

    // Sum across the 16 column-lanes within each lane-group.
#pragma unroll
    for (int mi = 0; mi < 4; ++mi)
#pragma unroll
        for (int r = 0; r < 4; ++r) {
            float v = rowsum[mi][r];
            v += __shfl_xor(v, 1, 64);
            v += __shfl_xor(v, 2, 64);
            v += __shfl_xor(v, 4, 64);
            v += __shfl_xor(v, 8, 64);
            rowsum[mi][r] = v;
        }

    // Combine the two ni-halves of each row via LDS scratch, then write.
    __syncthreads();
    if (ng == 0 && l15 == 0) {
#pragma unroll
        for (int mi = 0; mi < 4; ++mi)
#pragma unroll
            for (int r = 0; r < 4; ++r)
                red[rg * 64 + mi * 16 + lg * 4 + r] = rowsum[mi][r];
    }
    __syncthreads();
    if (ng == 1 && l15 == 0) {
#pragma unroll
        for (int mi = 0; mi < 4; ++mi)
#pragma unroll
            for (int r = 0; r < 4; ++r) {
                const int rr = rg * 64 + mi * 16 + lg * 4 + r;
                partial[csp * TWO_B + rt * 256 + rr] = rowsum[mi][r] + red[rr];
            }
    }
}

// ---------------------------------------------------------------------------
// Kernel 3: thread-per-row finalize + fused mean. [unchanged]
// ---------------------------------------------------------------------------
__global__ __launch_bounds__(256) void fk(const float* __restrict__ partial,
                                          const float* __restrict__ posv,
                                          const float* __restrict__ sqv,
                                          float* __restrict__ out) {
    const int row = blockIdx.x * 256 + threadIdx.x;
    float S = 0.0f;
#pragma unroll
    for (int c = 0; c < NSPL; ++c) S += partial[c * TWO_B + row];
    const float pos = posv[row], sq = sqv[row];
    S += EXP2F(pos * SCALE) - EXP2F(sq);
    float loss = __logf(S) - pos * INV_T;
#pragma unroll
    for (int m = 1; m < 64; m <<= 1) loss += __shfl_xor(loss, m, 64);
    __shared__ float acc[4];
    if ((threadIdx.x & 63) == 0) acc[threadIdx.x >> 6] = loss;
    __syncthreads();
    if (threadIdx.x == 0)
        atomicAdd(out, (acc[0] + acc[1] + acc[2] + acc[3]) * (1.0f / TWO_B));
}

extern "C" void kernel_launch(void* const* d_in, const int* in_sizes, int n_in,
                              void* d_out, int out_size, void* d_ws, size_t ws_size,
                              hipStream_t stream) {
    const float* zi = (const float*)d_in[0];
    const float* zj = (const float*)d_in[1];
    char* ws = (char*)d_ws;
    unsigned char* n8      = (unsigned char*)ws;                         // 1 MB
    float*         partial = (float*)(ws + (size_t)TWO_B * CDIM);        // 512 KB
    float*         posv    = (float*)(ws + (size_t)TWO_B * CDIM + (size_t)NSPL * TWO_B * 4);
    float*         sqv     = posv + TWO_B;                               // 32 KB each

    nk<<<TWO_B / 16, 256, 0, stream>>>(zi, zj, n8, posv, sqv, (float*)d_out);
    sk<<<dim3(32, NSPL), 512, 0, stream>>>(n8, partial);
    fk<<<32, 256, 0, stream>>>(partial, posv, sqv, (float*)d_out);
}

// Round 4
// 73.500 us; speedup vs baseline: 1.3946x; 1.3946x over previous
//
#include <hip/hip_runtime.h>
#include <hip/hip_bf16.h>

typedef int   intx8   __attribute__((ext_vector_type(8)));
typedef int   intx4   __attribute__((ext_vector_type(4)));
typedef float floatx4 __attribute__((ext_vector_type(4)));

static constexpr int TWO_B = 8192;   // 2*B rows
static constexpr int CDIM  = 128;    // feature dim
static constexpr int NSPL  = 16;     // column splits (R6-proven)
// exp(x/T) = exp2(x * (1/T)/ln2), T = 0.5
#define SCALE 2.8853900817779268f
#define SQS   1.6986436f             // sqrt(SCALE): n8 rows pre-scaled by this,
                                     // so MFMA output is already in exp2 domain
#define INV_T 2.0f

#if __has_builtin(__builtin_amdgcn_exp2f)
#define EXP2F(x) __builtin_amdgcn_exp2f(x)
#else
#define EXP2F(x) exp2f(x)
#endif

// e8m0 scale byte 0x7F = 2^0 = 1.0 in all four byte slots
#define SCL1 0x7F7F7F7F

// ---------------------------------------------------------------------------
// Kernel 1: pair-structured normalize, 2 pairs per wave (512 blocks).
// [unchanged]
// ---------------------------------------------------------------------------
__global__ __launch_bounds__(256) void nk(const float* __restrict__ zi,
                                          const float* __restrict__ zj,
                                          unsigned char* __restrict__ n8,
                                          float* __restrict__ posv,
                                          float* __restrict__ sqv,
                                          float* __restrict__ outz) {
    if (blockIdx.x == 0 && threadIdx.x == 0) *outz = 0.0f;
    const int w = threadIdx.x >> 6, lane = threadIdx.x & 63;
    const int half = lane >> 5;            // 0: zi row, 1: zj row
    const int l32  = lane & 31;
#pragma unroll
    for (int pi = 0; pi < 2; ++pi) {
        const int pr = (blockIdx.x * 4 + w) * 2 + pi;   // pair index 0..4095
        const float* src = half ? (zj + (size_t)pr * CDIM) : (zi + (size_t)pr * CDIM);
        float4 x = reinterpret_cast<const float4*>(src)[l32];
        float ss = x.x * x.x + x.y * x.y + x.z * x.z + x.w * x.w;
#pragma unroll
        for (int m = 1; m < 32; m <<= 1) ss += __shfl_xor(ss, m, 64);  // within-half
        const float rn = rsqrtf(ss);
        float4 y; y.x = x.x * rn; y.y = x.y * rn; y.z = x.z * rn; y.w = x.w * rn;

        // fp32-exact positive dot: cross-half partner lanes.
        const float qx = __shfl_xor(y.x, 32, 64);
        const float qy = __shfl_xor(y.y, 32, 64);
        const float qz = __shfl_xor(y.z, 32, 64);
        const float qw = __shfl_xor(y.w, 32, 64);
        float d = y.x * qx + y.y * qy + y.z * qz + y.w * qw;
#pragma unroll
        for (int m = 1; m < 32; m <<= 1) d += __shfl_xor(d, m, 64);

        // fp8 row, pre-scaled so MFMA output is SCALE*sim.
        int p = __builtin_amdgcn_cvt_pk_fp8_f32(y.x * SQS, y.y * SQS, 0, false);
        p     = __builtin_amdgcn_cvt_pk_fp8_f32(y.z * SQS, y.w * SQS, p, true);
        const int row = pr + half * 4096;
        reinterpret_cast<int*>(n8 + (size_t)row * CDIM)[l32] = p;

        // self-sq from the stored bytes (already in exp2 domain).
        const float f0 = __builtin_amdgcn_cvt_f32_fp8(p, 0);
        const float f1 = __builtin_amdgcn_cvt_f32_fp8(p, 1);
        const float f2 = __builtin_amdgcn_cvt_f32_fp8(p, 2);
        const float f3 = __builtin_amdgcn_cvt_f32_fp8(p, 3);
        float sq = f0 * f0 + f1 * f1 + f2 * f2 + f3 * f3;
#pragma unroll
        for (int m = 1; m < 32; m <<= 1) sq += __shfl_xor(sq, m, 64);

        if (l32 == 0) { posv[row] = d; sqv[row] = sq; }
    }
}

// ---------------------------------------------------------------------------
// Kernel 2 [THIS ROUND]: R2 geometry reverted verbatim (8 waves x 32 rows,
// broadcast B, counted-vmcnt double-buffer — R3's N-split regressed 28us and
// its counters showed sk is TRAFFIC-bound: FETCH 56MB =~ full demand, L2
// re-reads missing). Added: bijective XCD-aware (rt,csp) tiling. Default
// round-robin gives each XCD all 16 csp values (1MB unique B under L2 thrash
// from the harness's 256MiB poison). New map: XCD x owns an 8x8 (rt,csp)
// tile -> unique working set/XCD = 256KB A + 512KB B, every line reused 8x
// through its own L2. Pure permutation of block work — bit-identical output.
// ---------------------------------------------------------------------------
__global__ __launch_bounds__(512, 4) void sk(const unsigned char* __restrict__ n8,
                                             float* __restrict__ partial) {
    // hw linear bid (x fastest); hw assigns bid -> XCD round-robin (bid&7).
    const int bid = blockIdx.x + 32 * blockIdx.y;
    const int x = bid & 7;          // xcd
    const int k = bid >> 3;         // 0..63 within xcd
    const int rt  = (x & 3) * 8 + (k & 7);    // 0..31 (row tile)
    const int csp = (x >> 2) * 8 + (k >> 3);  // 0..15 (col split)

    const int tid = threadIdx.x;
    const int w   = tid >> 6;     // 0..7
    const int lane = tid & 63;
    const int l15 = lane & 15;
    const int lg  = lane >> 4;

    __shared__ __align__(16) unsigned char ldsB[2][64 * CDIM];   // 2 x 8 KB

    // A fragments: 32 rows x 128 k per wave, registers.
    // f8f6f4 16x16x128 A-layout: m = lane&15, k = (lane>>4)*32 + j
    const int rowbase = rt * 256 + w * 32;
    intx8 afrag[2];
#pragma unroll
    for (int mi = 0; mi < 2; ++mi)
        afrag[mi] = *reinterpret_cast<const intx8*>(
            n8 + (size_t)(rowbase + mi * 16 + l15) * CDIM + lg * 32);

    float rowsum[2][4];
#pragma unroll
    for (int mi = 0; mi < 2; ++mi)
#pragma unroll
        for (int r = 0; r < 4; ++r) rowsum[mi][r] = 0.0f;

    const int colbase0 = csp * 512;

    // Issue the single global_load_lds for column-stage ct into ldsB[buf].
    // LDS 16B-slot s holds global chunk (R = s>>3, c = (s&7) ^ (R&7)) —
    // swizzle on the global side (global_load_lds dest is lane-linear).
    auto stage = [&](int buf, int ct) {
        const int s = tid;                        // 0..511: uniform base + lane*16
        const int R = s >> 3, cs = s & 7;
        const int gc = cs ^ (R & 7);
        const unsigned char* g =
            n8 + (size_t)(colbase0 + ct * 64 + R) * CDIM + gc * 16;
        __builtin_amdgcn_global_load_lds(
            (__attribute__((address_space(1))) void*)g,
            (__attribute__((address_space(3))) void*)(&ldsB[buf][0] + s * 16),
            16, 0, 0);
    };

    stage(0, 0);   // prologue: stage-0 load in flight

#pragma unroll
    for (int ct = 0; ct < 8; ++ct) {
        const int cur = ct & 1;
        if (ct < 7) {
            stage(cur ^ 1, ct + 1);               // prefetch next stage
            // wait only for stage-ct's load; the prefetch load stays in
            // flight across the barrier (never drain to 0 mid-loop).
            asm volatile("s_waitcnt vmcnt(1)" ::: "memory");
        } else {
            asm volatile("s_waitcnt vmcnt(0)" ::: "memory");
        }
        __builtin_amdgcn_s_barrier();
        asm volatile("" ::: "memory");            // pin ds_reads below barrier

#pragma unroll
        for (int ni = 0; ni < 4; ++ni) {
            // B-layout: n = lane&15 (local row R), k = (lane>>4)*32 + j
            const int R  = ni * 16 + l15;
            const int c0 = lg * 2;
            const int p0 = R * 8 + (c0 ^ (R & 7));
            const int p1 = R * 8 + ((c0 + 1) ^ (R & 7));
            intx4 blo = *reinterpret_cast<const intx4*>(&ldsB[cur][0] + p0 * 16);
            intx4 bhi = *reinterpret_cast<const intx4*>(&ldsB[cur][0] + p1 * 16);
            intx8 bfrag;
            bfrag[0] = blo[0]; bfrag[1] = blo[1]; bfrag[2] = blo[2]; bfrag[3] = blo[3];
            bfrag[4] = bhi[0]; bfrag[5] = bhi[1]; bfrag[6] = bhi[2]; bfrag[7] = bhi[3];
#pragma unroll
            for (int mi = 0; mi < 2; ++mi) {
                floatx4 acc = {0.f, 0.f, 0.f, 0.f};
                acc = __builtin_amdgcn_mfma_scale_f32_16x16x128_f8f6f4(
                    afrag[mi], bfrag, acc, 0, 0, 0, SCL1, 0, SCL1);
                // C/D layout: col = lane&15, row = (lane>>4)*4 + reg
#pragma unroll
                for (int r = 0; r < 4; ++r)
                    rowsum[mi][r] += EXP2F(acc[r]);   // acc is already SCALE*sim
            }
        }

        if (ct < 7) {
            // all waves done reading ldsB[cur] before stage ct+2 overwrites it
            asm volatile("" ::: "memory");
            __builtin_amdgcn_s_barrier();
        }
    }

    // Sum across the 16 column-lanes within each lane-group.
#pragma unroll
    for (int mi = 0; mi < 2; ++mi)
#pragma unroll
        for (int r = 0; r < 4; ++r) {
            float v = rowsum[mi][r];
            v += __shfl_xor(v, 1, 64);
            v += __shfl_xor(v, 2, 64);
            v += __shfl_xor(v, 4, 64);
            v += __shfl_xor(v, 8, 64);
            rowsum[mi][r] = v;
        }
    if (l15 == 0) {
#pragma unroll
        for (int mi = 0; mi < 2; ++mi)
#pragma unroll
            for (int r = 0; r < 4; ++r)
                partial[csp * TWO_B + rowbase + mi * 16 + lg * 4 + r] = rowsum[mi][r];
    }
}

// ---------------------------------------------------------------------------
// Kernel 3: thread-per-row finalize + fused mean. [unchanged]
// ---------------------------------------------------------------------------
__global__ __launch_bounds__(256) void fk(const float* __restrict__ partial,
                                          const float* __restrict__ posv,
                                          const float* __restrict__ sqv,
                                          float* __restrict__ out) {
    const int row = blockIdx.x * 256 + threadIdx.x;
    float S = 0.0f;
#pragma unroll
    for (int c = 0; c < NSPL; ++c) S += partial[c * TWO_B + row];
    const float pos = posv[row], sq = sqv[row];
    S += EXP2F(pos * SCALE) - EXP2F(sq);
    float loss = __logf(S) - pos * INV_T;
#pragma unroll
    for (int m = 1; m < 64; m <<= 1) loss += __shfl_xor(loss, m, 64);
    __shared__ float acc[4];
    if ((threadIdx.x & 63) == 0) acc[threadIdx.x >> 6] = loss;
    __syncthreads();
    if (threadIdx.x == 0)
        atomicAdd(out, (acc[0] + acc[1] + acc[2] + acc[3]) * (1.0f / TWO_B));
}

extern "C" void kernel_launch(void* const* d_in, const int* in_sizes, int n_in,
                              void* d_out, int out_size, void* d_ws, size_t ws_size,
                              hipStream_t stream) {
    const float* zi = (const float*)d_in[0];
    const float* zj = (const float*)d_in[1];
    char* ws = (char*)d_ws;
    unsigned char* n8      = (unsigned char*)ws;                         // 1 MB
    float*         partial = (float*)(ws + (size_t)TWO_B * CDIM);        // 512 KB
    float*         posv    = (float*)(ws + (size_t)TWO_B * CDIM + (size_t)NSPL * TWO_B * 4);
    float*         sqv     = posv + TWO_B;                               // 32 KB each

    nk<<<TWO_B / 16, 256, 0, stream>>>(zi, zj, n8, posv, sqv, (float*)d_out);
    sk<<<dim3(32, NSPL), 512, 0, stream>>>(n8, partial);
    fk<<<32, 256, 0, stream>>>(partial, posv, sqv, (float*)d_out);
}